// Round 4
// baseline (383.048 us; speedup 1.0000x reference)
//
#include <hip/hip_runtime.h>

#define LMBDA 0.001f
#define NS_SPD 10   // Newton-Schulz iters for SPD H1/G1
#define NS_SX  6    // Newton-Schulz iters for sx
#define OUTER  6    // outer preconditioned-Richardson iterations

// workspace layout (float offsets)
#define WS_A    0        // 64*256
#define WS_FY   16384    // 64*256
#define WS_H1   32768
#define WS_G1   36864
#define WS_HINV 40960
#define WS_GINV 45056
#define WS_R2   49152
#define WS_R4   53248
#define WS_T1   57344
#define WS_RHS  61440
// total 65536 floats = 256 KiB

// XOR swizzle: conflict-free column (fixed-k) reads on stride-64 buffers
#define SIDX(i,k) (((i) << 6) | ((k) ^ ((i) & 31)))

// ---------------- Kernel 1: A = tx@fx, Fy = ty@fy  (64x5000 @ 5000x256) ----
__global__ __launch_bounds__(256) void k1_gemm(
    const float* __restrict__ tx, const float* __restrict__ fx,
    const float* __restrict__ ty, const float* __restrict__ fy,
    float* __restrict__ wsA, float* __restrict__ wsFy)
{
    __shared__ float stx[64 * 65];
    __shared__ float sfx[64 * 65];
    const int tid = threadIdx.x;
    const int ti = tid >> 4, tj = tid & 15;
    const int mat = blockIdx.x >> 2;
    const int m0 = (blockIdx.x & 3) << 6;
    const float* __restrict__ T = mat ? ty : tx;
    const float* __restrict__ F = mat ? fy : fx;
    float* __restrict__ Out = mat ? wsFy : wsA;

    float acc[4][4];
    #pragma unroll
    for (int r = 0; r < 4; ++r)
        #pragma unroll
        for (int c = 0; c < 4; ++c) acc[r][c] = 0.f;

    for (int sc = blockIdx.y; sc * 64 < 5000; sc += gridDim.y) {
        const int v0 = sc << 6;
        int vlen = 5000 - v0; if (vlen > 64) vlen = 64;
        #pragma unroll
        for (int w = 0; w < 4; ++w) {
            const int fidx = tid + (w << 8);
            const int row = fidx >> 4, q = fidx & 15;
            const int vv = q << 2;
            if (vv < vlen) {
                float4 val = *(const float4*)(T + (size_t)row * 5000 + v0 + vv);
                stx[row * 65 + vv + 0] = val.x;
                stx[row * 65 + vv + 1] = val.y;
                stx[row * 65 + vv + 2] = val.z;
                stx[row * 65 + vv + 3] = val.w;
            }
            if (row < vlen) {
                float4 val = *(const float4*)(F + (size_t)(v0 + row) * 256 + m0 + (q << 2));
                sfx[row * 65 + (q << 2) + 0] = val.x;
                sfx[row * 65 + (q << 2) + 1] = val.y;
                sfx[row * 65 + (q << 2) + 2] = val.z;
                sfx[row * 65 + (q << 2) + 3] = val.w;
            }
        }
        __syncthreads();
        for (int vv = 0; vv < vlen; ++vv) {
            float a[4], b[4];
            #pragma unroll
            for (int r = 0; r < 4; ++r) a[r] = stx[(4 * ti + r) * 65 + vv];
            #pragma unroll
            for (int c = 0; c < 4; ++c) b[c] = sfx[vv * 65 + 4 * tj + c];
            #pragma unroll
            for (int r = 0; r < 4; ++r)
                #pragma unroll
                for (int c = 0; c < 4; ++c)
                    acc[r][c] = fmaf(a[r], b[c], acc[r][c]);
        }
        __syncthreads();
    }
    #pragma unroll
    for (int r = 0; r < 4; ++r)
        #pragma unroll
        for (int c = 0; c < 4; ++c)
            atomicAdd(&Out[(4 * ti + r) * 256 + m0 + 4 * tj + c], acc[r][c]);
}

// ---- Newton-Schulz in-LDS inversion on SIDX-swizzled buffers -------------
// X <- X(2I - M X), X0 = alpha*I. M,X,Y are flat-4096 swizzled LDS.
__device__ __forceinline__ void ns_invert(float* M, float* X, float* Y,
                                          int iters, int ti, int tj,
                                          int tid, float alpha)
{
    for (int idx = tid; idx < 4096; idx += 256) {
        int i = idx >> 6, j = idx & 63;
        X[SIDX(i, j)] = (i == j) ? alpha : 0.f;
    }
    __syncthreads();
    for (int it = 0; it < iters; ++it) {
        // Y = M * X
        float y[4][4];
        #pragma unroll
        for (int r = 0; r < 4; ++r)
            #pragma unroll
            for (int c = 0; c < 4; ++c) y[r][c] = 0.f;
        for (int k = 0; k < 64; ++k) {
            float mv[4], xv[4];
            #pragma unroll
            for (int r = 0; r < 4; ++r) mv[r] = M[SIDX(4 * ti + r, k)];
            #pragma unroll
            for (int c = 0; c < 4; ++c) xv[c] = X[SIDX(k, 4 * tj + c)];
            #pragma unroll
            for (int r = 0; r < 4; ++r)
                #pragma unroll
                for (int c = 0; c < 4; ++c) y[r][c] = fmaf(mv[r], xv[c], y[r][c]);
        }
        #pragma unroll
        for (int r = 0; r < 4; ++r)
            #pragma unroll
            for (int c = 0; c < 4; ++c)
                Y[SIDX(4 * ti + r, 4 * tj + c)] = y[r][c];
        __syncthreads();
        // Z = X * Y ; X = 2X - Z
        float z[4][4];
        #pragma unroll
        for (int r = 0; r < 4; ++r)
            #pragma unroll
            for (int c = 0; c < 4; ++c) z[r][c] = 0.f;
        for (int k = 0; k < 64; ++k) {
            float xr[4], yv[4];
            #pragma unroll
            for (int r = 0; r < 4; ++r) xr[r] = X[SIDX(4 * ti + r, k)];
            #pragma unroll
            for (int c = 0; c < 4; ++c) yv[c] = Y[SIDX(k, 4 * tj + c)];
            #pragma unroll
            for (int r = 0; r < 4; ++r)
                #pragma unroll
                for (int c = 0; c < 4; ++c) z[r][c] = fmaf(xr[r], yv[c], z[r][c]);
        }
        __syncthreads();
        #pragma unroll
        for (int r = 0; r < 4; ++r)
            #pragma unroll
            for (int c = 0; c < 4; ++c) {
                int s = SIDX(4 * ti + r, 4 * tj + c);
                X[s] = 2.f * X[s] - z[r][c];
            }
        __syncthreads();
    }
}

// ---------------- Kernel 2: 4 specialized blocks ---------------------------
// b0: H1 -> ws, NS-> Hinv   b1: G1 -> ws, NS-> Ginv
// b2: P=NS(sx); R2/R4/T1    b3: FyAT, H1 (local), RHS = H1*FyAT -> ws
__global__ __launch_bounds__(256) void k2_prep(
    const float* __restrict__ wsA, const float* __restrict__ wsFy,
    const float* __restrict__ sx, const float* __restrict__ sy,
    const float* __restrict__ ex, float* __restrict__ ws)
{
    __shared__ __align__(16) float sA[4096];   // flat row-major (row-fixed use)
    __shared__ float sM[4096];                 // SIDX
    __shared__ float sX[4096];                 // SIDX
    __shared__ float sY[4096];                 // SIDX
    const int tid = threadIdx.x;
    const int ti = tid >> 4, tj = tid & 15;
    const int b = blockIdx.x;

    if (b == 0 || b == 1) {
        // build SPD matrix into sM[SIDX] (+ store to ws)
        float a[4][4];
        #pragma unroll
        for (int r = 0; r < 4; ++r)
            #pragma unroll
            for (int c = 0; c < 4; ++c) a[r][c] = 0.f;
        if (b == 0) {
            // stage sy flat; H1 = sy^T sy
            for (int idx = tid; idx < 1024; idx += 256) {
                int i = idx >> 4, j4 = (idx & 15) << 2;
                *(float4*)&sA[i * 64 + j4] = *(const float4*)&sy[i * 64 + j4];
            }
            __syncthreads();
            for (int k = 0; k < 64; ++k) {
                float4 av = *(const float4*)&sA[k * 64 + 4 * ti];
                float4 bv = *(const float4*)&sA[k * 64 + 4 * tj];
                float avv[4] = {av.x, av.y, av.z, av.w};
                #pragma unroll
                for (int r = 0; r < 4; ++r) {
                    a[r][0] = fmaf(avv[r], bv.x, a[r][0]);
                    a[r][1] = fmaf(avv[r], bv.y, a[r][1]);
                    a[r][2] = fmaf(avv[r], bv.z, a[r][2]);
                    a[r][3] = fmaf(avv[r], bv.w, a[r][3]);
                }
            }
        } else {
            // G1 = A A^T over 4 chunks (transposed staging)
            for (int ch = 0; ch < 4; ++ch) {
                for (int idx = tid; idx < 1024; idx += 256) {
                    int i = idx >> 4, m4 = (idx & 15) << 2;
                    float4 v = *(const float4*)&wsA[i * 256 + (ch << 6) + m4];
                    sA[(m4 + 0) * 64 + i] = v.x;
                    sA[(m4 + 1) * 64 + i] = v.y;
                    sA[(m4 + 2) * 64 + i] = v.z;
                    sA[(m4 + 3) * 64 + i] = v.w;
                }
                __syncthreads();
                for (int m = 0; m < 64; ++m) {
                    float4 av = *(const float4*)&sA[m * 64 + 4 * ti];
                    float4 bv = *(const float4*)&sA[m * 64 + 4 * tj];
                    float avv[4] = {av.x, av.y, av.z, av.w};
                    #pragma unroll
                    for (int r = 0; r < 4; ++r) {
                        a[r][0] = fmaf(avv[r], bv.x, a[r][0]);
                        a[r][1] = fmaf(avv[r], bv.y, a[r][1]);
                        a[r][2] = fmaf(avv[r], bv.z, a[r][2]);
                        a[r][3] = fmaf(avv[r], bv.w, a[r][3]);
                    }
                }
                __syncthreads();
            }
        }
        const int wsoff = (b == 0) ? WS_H1 : WS_G1;
        #pragma unroll
        for (int r = 0; r < 4; ++r)
            #pragma unroll
            for (int c = 0; c < 4; ++c) {
                sM[SIDX(4 * ti + r, 4 * tj + c)] = a[r][c];
                ws[wsoff + (4 * ti + r) * 64 + 4 * tj + c] = a[r][c];
            }
        __syncthreads();
        // Gershgorin alpha = 1/max row-sum (sA is dead scratch now)
        if (tid < 64) {
            float s = 0.f;
            for (int j = 0; j < 64; ++j) s += fabsf(sM[SIDX(tid, j)]);
            sA[tid] = s;
        }
        __syncthreads();
        float mx = 0.f;
        for (int i = 0; i < 64; ++i) mx = fmaxf(mx, sA[i]);
        ns_invert(sM, sX, sY, NS_SPD, ti, tj, tid, 1.0f / mx);
        const int wsinv = (b == 0) ? WS_HINV : WS_GINV;
        for (int idx = tid; idx < 1024; idx += 256) {
            int i = idx >> 4, j4 = (idx & 15) << 2;
            float4 v = {sX[SIDX(i, j4 + 0)], sX[SIDX(i, j4 + 1)],
                        sX[SIDX(i, j4 + 2)], sX[SIDX(i, j4 + 3)]};
            *(float4*)&ws[wsinv + i * 64 + j4] = v;
        }
    } else if (b == 2) {
        // P = inv(sx) via NS (X0 = I); then R2/R4/T1
        for (int idx = tid; idx < 1024; idx += 256) {
            int i = idx >> 4, j4 = (idx & 15) << 2;
            float4 v = *(const float4*)&sx[i * 64 + j4];
            sM[SIDX(i, j4 + 0)] = v.x;
            sM[SIDX(i, j4 + 1)] = v.y;
            sM[SIDX(i, j4 + 2)] = v.z;
            sM[SIDX(i, j4 + 3)] = v.w;
        }
        if (tid < 64) sA[tid] = ex[tid];
        __syncthreads();
        ns_invert(sM, sX, sY, NS_SX, ti, tj, tid, 1.0f);
        float aR2[4][4], aR4[4][4], aT1[4][4];
        #pragma unroll
        for (int r = 0; r < 4; ++r)
            #pragma unroll
            for (int c = 0; c < 4; ++c) { aR2[r][c] = 0.f; aR4[r][c] = 0.f; aT1[r][c] = 0.f; }
        for (int k = 0; k < 64; ++k) {
            float e = sA[k], e2 = e * e;
            float av[4], bv[4];
            #pragma unroll
            for (int r = 0; r < 4; ++r) av[r] = sX[SIDX(k, 4 * ti + r)];
            #pragma unroll
            for (int c = 0; c < 4; ++c) bv[c] = sX[SIDX(k, 4 * tj + c)];
            #pragma unroll
            for (int r = 0; r < 4; ++r)
                #pragma unroll
                for (int c = 0; c < 4; ++c) {
                    float p = av[r] * bv[c];
                    aR4[r][c] += p;
                    aR2[r][c] = fmaf(e, p, aR2[r][c]);
                    aT1[r][c] = fmaf(e2, p, aT1[r][c]);
                }
        }
        #pragma unroll
        for (int r = 0; r < 4; ++r)
            #pragma unroll
            for (int c = 0; c < 4; ++c) {
                int o = (4 * ti + r) * 64 + 4 * tj + c;
                ws[WS_R2 + o] = aR2[r][c];
                ws[WS_R4 + o] = aR4[r][c];
                ws[WS_T1 + o] = aT1[r][c];
            }
    } else {
        // FyAT = Fy A^T (regs) -> sX ; H1 (local) -> sM ; RHS = H1*FyAT -> ws
        float a[4][4];
        #pragma unroll
        for (int r = 0; r < 4; ++r)
            #pragma unroll
            for (int c = 0; c < 4; ++c) a[r][c] = 0.f;
        for (int ch = 0; ch < 4; ++ch) {
            for (int idx = tid; idx < 1024; idx += 256) {
                int i = idx >> 4, m4 = (idx & 15) << 2;
                float4 v = *(const float4*)&wsFy[i * 256 + (ch << 6) + m4];
                sA[(m4 + 0) * 64 + i] = v.x;
                sA[(m4 + 1) * 64 + i] = v.y;
                sA[(m4 + 2) * 64 + i] = v.z;
                sA[(m4 + 3) * 64 + i] = v.w;
                float4 w = *(const float4*)&wsA[i * 256 + (ch << 6) + m4];
                sM[(m4 + 0) * 64 + i] = w.x;
                sM[(m4 + 1) * 64 + i] = w.y;
                sM[(m4 + 2) * 64 + i] = w.z;
                sM[(m4 + 3) * 64 + i] = w.w;
            }
            __syncthreads();
            for (int m = 0; m < 64; ++m) {
                float4 fv = *(const float4*)&sA[m * 64 + 4 * ti];
                float4 av = *(const float4*)&sM[m * 64 + 4 * tj];
                float fvv[4] = {fv.x, fv.y, fv.z, fv.w};
                #pragma unroll
                for (int r = 0; r < 4; ++r) {
                    a[r][0] = fmaf(fvv[r], av.x, a[r][0]);
                    a[r][1] = fmaf(fvv[r], av.y, a[r][1]);
                    a[r][2] = fmaf(fvv[r], av.z, a[r][2]);
                    a[r][3] = fmaf(fvv[r], av.w, a[r][3]);
                }
            }
            __syncthreads();
        }
        // FyAT -> sX[SIDX]
        #pragma unroll
        for (int r = 0; r < 4; ++r)
            #pragma unroll
            for (int c = 0; c < 4; ++c)
                sX[SIDX(4 * ti + r, 4 * tj + c)] = a[r][c];
        // stage sy -> sA
        for (int idx = tid; idx < 1024; idx += 256) {
            int i = idx >> 4, j4 = (idx & 15) << 2;
            *(float4*)&sA[i * 64 + j4] = *(const float4*)&sy[i * 64 + j4];
        }
        __syncthreads();
        // H1 = sy^T sy -> sM[SIDX]
        float h[4][4];
        #pragma unroll
        for (int r = 0; r < 4; ++r)
            #pragma unroll
            for (int c = 0; c < 4; ++c) h[r][c] = 0.f;
        for (int k = 0; k < 64; ++k) {
            float4 av = *(const float4*)&sA[k * 64 + 4 * ti];
            float4 bv = *(const float4*)&sA[k * 64 + 4 * tj];
            float avv[4] = {av.x, av.y, av.z, av.w};
            #pragma unroll
            for (int r = 0; r < 4; ++r) {
                h[r][0] = fmaf(avv[r], bv.x, h[r][0]);
                h[r][1] = fmaf(avv[r], bv.y, h[r][1]);
                h[r][2] = fmaf(avv[r], bv.z, h[r][2]);
                h[r][3] = fmaf(avv[r], bv.w, h[r][3]);
            }
        }
        #pragma unroll
        for (int r = 0; r < 4; ++r)
            #pragma unroll
            for (int c = 0; c < 4; ++c)
                sM[SIDX(4 * ti + r, 4 * tj + c)] = h[r][c];
        __syncthreads();
        // RHS = H1 * FyAT
        float rh[4][4];
        #pragma unroll
        for (int r = 0; r < 4; ++r)
            #pragma unroll
            for (int c = 0; c < 4; ++c) rh[r][c] = 0.f;
        for (int k = 0; k < 64; ++k) {
            float hv[4], tv[4];
            #pragma unroll
            for (int r = 0; r < 4; ++r) hv[r] = sM[SIDX(4 * ti + r, k)];
            #pragma unroll
            for (int c = 0; c < 4; ++c) tv[c] = sX[SIDX(k, 4 * tj + c)];
            #pragma unroll
            for (int r = 0; r < 4; ++r)
                #pragma unroll
                for (int c = 0; c < 4; ++c) rh[r][c] = fmaf(hv[r], tv[c], rh[r][c]);
        }
        #pragma unroll
        for (int r = 0; r < 4; ++r) {
            float4 v = {rh[r][0], rh[r][1], rh[r][2], rh[r][3]};
            *(float4*)&ws[WS_RHS + (4 * ti + r) * 64 + 4 * tj] = v;
        }
    }
}

// ---------------- Kernel 3: preconditioned Richardson solve (one block) ----
// 144 KiB dynamic LDS: 5 constant matrices + 4 swizzled work buffers.
__global__ __launch_bounds__(256) void k3_solve(
    const float* __restrict__ ws, const float* __restrict__ ey_g,
    float* __restrict__ out)
{
    extern __shared__ __align__(16) float lds[];
    float* cGinv = lds;             // row-major, read row-k-fixed
    float* cHinv = lds + 4096;
    float* cM1   = lds + 8192;      // = G1 + LMBDA*T1
    float* cR2   = lds + 12288;
    float* cR4   = lds + 16384;
    float* sX    = lds + 20480;     // SIDX
    float* sR    = lds + 24576;     // SIDX
    float* sT0   = lds + 28672;     // SIDX
    float* sT1   = lds + 32768;     // SIDX
    const int tid = threadIdx.x;
    const int ti = tid >> 4, tj = tid & 15;
    const float* __restrict__ H1g  = ws + WS_H1;
    const float* __restrict__ G1g  = ws + WS_G1;
    const float* __restrict__ T1g  = ws + WS_T1;
    const float* __restrict__ Ginvg = ws + WS_GINV;
    const float* __restrict__ Hinvg = ws + WS_HINV;
    const float* __restrict__ R2g  = ws + WS_R2;
    const float* __restrict__ R4g  = ws + WS_R4;
    const float* __restrict__ RHSg = ws + WS_RHS;

    // stage constants
    for (int idx = tid; idx < 1024; idx += 256) {
        int i = idx >> 4, j4 = (idx & 15) << 2;
        int o = i * 64 + j4;
        *(float4*)&cGinv[o] = *(const float4*)&Ginvg[o];
        *(float4*)&cHinv[o] = *(const float4*)&Hinvg[o];
        *(float4*)&cR2[o]   = *(const float4*)&R2g[o];
        *(float4*)&cR4[o]   = *(const float4*)&R4g[o];
        float4 g = *(const float4*)&G1g[o];
        float4 t = *(const float4*)&T1g[o];
        float4 m = {fmaf(LMBDA, t.x, g.x), fmaf(LMBDA, t.y, g.y),
                    fmaf(LMBDA, t.z, g.z), fmaf(LMBDA, t.w, g.w)};
        *(float4*)&cM1[o] = m;
    }
    float4 eyv = *(const float4*)&ey_g[4 * ti];
    float eyr[4] = {eyv.x, eyv.y, eyv.z, eyv.w};
    float leyr[4];
    #pragma unroll
    for (int r = 0; r < 4; ++r) leyr[r] = LMBDA * eyr[r];

    // rhs tile -> regs; init sR, sX
    float rhs[4][4];
    #pragma unroll
    for (int r = 0; r < 4; ++r) {
        float4 v = *(const float4*)&RHSg[(4 * ti + r) * 64 + 4 * tj];
        rhs[r][0] = v.x; rhs[r][1] = v.y; rhs[r][2] = v.z; rhs[r][3] = v.w;
        #pragma unroll
        for (int c = 0; c < 4; ++c) {
            sR[SIDX(4 * ti + r, 4 * tj + c)] = rhs[r][c];
            sX[SIDX(4 * ti + r, 4 * tj + c)] = 0.f;
        }
    }
    __syncthreads();

    for (int it = 0; it < OUTER; ++it) {
        // P1: T0 = R * Ginv
        {
            float a[4][4];
            #pragma unroll
            for (int r = 0; r < 4; ++r)
                #pragma unroll
                for (int c = 0; c < 4; ++c) a[r][c] = 0.f;
            for (int k = 0; k < 64; ++k) {
                float rv[4];
                #pragma unroll
                for (int r = 0; r < 4; ++r) rv[r] = sR[SIDX(4 * ti + r, k)];
                float4 gv = *(const float4*)&cGinv[k * 64 + 4 * tj];
                #pragma unroll
                for (int r = 0; r < 4; ++r) {
                    a[r][0] = fmaf(rv[r], gv.x, a[r][0]);
                    a[r][1] = fmaf(rv[r], gv.y, a[r][1]);
                    a[r][2] = fmaf(rv[r], gv.z, a[r][2]);
                    a[r][3] = fmaf(rv[r], gv.w, a[r][3]);
                }
            }
            #pragma unroll
            for (int r = 0; r < 4; ++r)
                #pragma unroll
                for (int c = 0; c < 4; ++c) sT0[SIDX(4 * ti + r, 4 * tj + c)] = a[r][c];
        }
        __syncthreads();
        // P2: X += Hinv * T0 (Hinv symmetric -> row-k-fixed f4)
        {
            float a[4][4];
            #pragma unroll
            for (int r = 0; r < 4; ++r)
                #pragma unroll
                for (int c = 0; c < 4; ++c) a[r][c] = 0.f;
            for (int k = 0; k < 64; ++k) {
                float4 hv = *(const float4*)&cHinv[k * 64 + 4 * ti];
                float hvv[4] = {hv.x, hv.y, hv.z, hv.w};
                float tv[4];
                #pragma unroll
                for (int c = 0; c < 4; ++c) tv[c] = sT0[SIDX(k, 4 * tj + c)];
                #pragma unroll
                for (int r = 0; r < 4; ++r)
                    #pragma unroll
                    for (int c = 0; c < 4; ++c) a[r][c] = fmaf(hvv[r], tv[c], a[r][c]);
            }
            #pragma unroll
            for (int r = 0; r < 4; ++r) {
                float nx[4];
                #pragma unroll
                for (int c = 0; c < 4; ++c) {
                    int s = SIDX(4 * ti + r, 4 * tj + c);
                    nx[c] = sX[s] + a[r][c];
                    sX[s] = nx[c];
                }
                if (it == OUTER - 1) {
                    float4 v = {nx[0], nx[1], nx[2], nx[3]};
                    *(float4*)&out[(4 * ti + r) * 64 + 4 * tj] = v;
                }
            }
        }
        if (it == OUTER - 1) break;
        __syncthreads();
        // P3: E1 = X M1 - l D X R2 -> T0 ; T1 = l(D X R4 - X R2)
        {
            float a1[4][4], a2[4][4];
            #pragma unroll
            for (int r = 0; r < 4; ++r)
                #pragma unroll
                for (int c = 0; c < 4; ++c) { a1[r][c] = 0.f; a2[r][c] = 0.f; }
            for (int k = 0; k < 64; ++k) {
                float xv[4];
                #pragma unroll
                for (int r = 0; r < 4; ++r) xv[r] = sX[SIDX(4 * ti + r, k)];
                float4 mv = *(const float4*)&cM1[k * 64 + 4 * tj];
                float4 qv = *(const float4*)&cR2[k * 64 + 4 * tj];
                float4 r4 = *(const float4*)&cR4[k * 64 + 4 * tj];
                float mvv[4] = {mv.x, mv.y, mv.z, mv.w};
                float qvv[4] = {qv.x, qv.y, qv.z, qv.w};
                float r4v[4] = {r4.x, r4.y, r4.z, r4.w};
                #pragma unroll
                for (int r = 0; r < 4; ++r)
                    #pragma unroll
                    for (int c = 0; c < 4; ++c) {
                        a1[r][c] = fmaf(xv[r], fmaf(-leyr[r], qvv[c], mvv[c]), a1[r][c]);
                        a2[r][c] = fmaf(xv[r], fmaf(eyr[r], r4v[c], -qvv[c]), a2[r][c]);
                    }
            }
            #pragma unroll
            for (int r = 0; r < 4; ++r)
                #pragma unroll
                for (int c = 0; c < 4; ++c) {
                    sT0[SIDX(4 * ti + r, 4 * tj + c)] = a1[r][c];
                    sT1[SIDX(4 * ti + r, 4 * tj + c)] = LMBDA * a2[r][c];
                }
        }
        __syncthreads();
        // P4: R = rhs - H1*(T0 + D.T1)  (H1 global, symmetric row reads)
        {
            float a[4][4];
            #pragma unroll
            for (int r = 0; r < 4; ++r)
                #pragma unroll
                for (int c = 0; c < 4; ++c) a[r][c] = 0.f;
            for (int k = 0; k < 64; ++k) {
                float4 hv = *(const float4*)&H1g[k * 64 + 4 * ti];
                float hvv[4] = {hv.x, hv.y, hv.z, hv.w};
                float t0v[4], t1v[4];
                #pragma unroll
                for (int c = 0; c < 4; ++c) {
                    t0v[c] = sT0[SIDX(k, 4 * tj + c)];
                    t1v[c] = sT1[SIDX(k, 4 * tj + c)];
                }
                #pragma unroll
                for (int r = 0; r < 4; ++r)
                    #pragma unroll
                    for (int c = 0; c < 4; ++c)
                        a[r][c] = fmaf(hvv[r], fmaf(eyr[r], t1v[c], t0v[c]), a[r][c]);
            }
            #pragma unroll
            for (int r = 0; r < 4; ++r)
                #pragma unroll
                for (int c = 0; c < 4; ++c)
                    sR[SIDX(4 * ti + r, 4 * tj + c)] = rhs[r][c] - a[r][c];
        }
        __syncthreads();
    }
}

extern "C" void kernel_launch(void* const* d_in, const int* in_sizes, int n_in,
                              void* d_out, int out_size, void* d_ws, size_t ws_size,
                              hipStream_t stream) {
    (void)in_sizes; (void)n_in; (void)out_size; (void)ws_size;
    const float* fx = (const float*)d_in[0];
    const float* fy = (const float*)d_in[1];
    const float* ex = (const float*)d_in[2];
    const float* ey = (const float*)d_in[3];
    const float* tx = (const float*)d_in[4];
    const float* ty = (const float*)d_in[5];
    const float* sx = (const float*)d_in[6];
    const float* sy = (const float*)d_in[7];
    float* ws = (float*)d_ws;
    float* out = (float*)d_out;

    // opt-in to >64KB dynamic LDS for k3 (idempotent; harmless if default ok)
    (void)hipFuncSetAttribute((const void*)k3_solve,
                              hipFuncAttributeMaxDynamicSharedMemorySize, 147456);

    (void)hipMemsetAsync(d_ws, 0, 2 * 64 * 256 * sizeof(float), stream);
    k1_gemm<<<dim3(8, 40), 256, 0, stream>>>(tx, fx, ty, fy, ws + WS_A, ws + WS_FY);
    k2_prep<<<4, 256, 0, stream>>>(ws + WS_A, ws + WS_FY, sx, sy, ex, ws);
    k3_solve<<<1, 256, 147456, stream>>>(ws, ey, out);
}

// Round 5
// 239.106 us; speedup vs baseline: 1.6020x; 1.6020x over previous
//
#include <hip/hip_runtime.h>

#define LMBDA 0.001f
#define NS_SPD 10   // Newton-Schulz iters for SPD H1/G1
#define NS_SX  6    // Newton-Schulz iters for sx
#define OUTER  6    // outer preconditioned-Richardson iterations
#define LDP 68      // padded stride for A-operand (row-slice) matrices

// workspace layout (float offsets)
#define WS_A    0        // 64*256
#define WS_FY   16384    // 64*256
#define WS_H1   32768
#define WS_G1   36864
#define WS_HINV 40960
#define WS_GINV 45056
#define WS_R2   49152
#define WS_R4   53248
#define WS_T1   57344
#define WS_RHS  61440

#define FMA4(ar, xs, b) { ar[0]=fmaf((xs),(b).x,ar[0]); ar[1]=fmaf((xs),(b).y,ar[1]); \
                          ar[2]=fmaf((xs),(b).z,ar[2]); ar[3]=fmaf((xs),(b).w,ar[3]); }

// C-tile += A[4ti..][:] * B[:][4tj..]; all f4 (b128) LDS reads, no column reads
template<int SA, int SB>
__device__ __forceinline__ void mm64(const float* __restrict__ A,
                                     const float* __restrict__ B,
                                     int ti, int tj, float a[4][4]) {
    #pragma unroll 4
    for (int k = 0; k < 64; k += 4) {
        float4 av0 = *(const float4*)&A[(4 * ti + 0) * SA + k];
        float4 av1 = *(const float4*)&A[(4 * ti + 1) * SA + k];
        float4 av2 = *(const float4*)&A[(4 * ti + 2) * SA + k];
        float4 av3 = *(const float4*)&A[(4 * ti + 3) * SA + k];
        float4 b0 = *(const float4*)&B[(k + 0) * SB + 4 * tj];
        float4 b1 = *(const float4*)&B[(k + 1) * SB + 4 * tj];
        float4 b2 = *(const float4*)&B[(k + 2) * SB + 4 * tj];
        float4 b3 = *(const float4*)&B[(k + 3) * SB + 4 * tj];
        FMA4(a[0], av0.x, b0); FMA4(a[0], av0.y, b1); FMA4(a[0], av0.z, b2); FMA4(a[0], av0.w, b3);
        FMA4(a[1], av1.x, b0); FMA4(a[1], av1.y, b1); FMA4(a[1], av1.z, b2); FMA4(a[1], av1.w, b3);
        FMA4(a[2], av2.x, b0); FMA4(a[2], av2.y, b1); FMA4(a[2], av2.z, b2); FMA4(a[2], av2.w, b3);
        FMA4(a[3], av3.x, b0); FMA4(a[3], av3.y, b1); FMA4(a[3], av3.z, b2); FMA4(a[3], av3.w, b3);
    }
}

// ---------------- Kernel 1: A = tx@fx, Fy = ty@fy  (64x5000 @ 5000x256) ----
__global__ __launch_bounds__(256) void k1_gemm(
    const float* __restrict__ tx, const float* __restrict__ fx,
    const float* __restrict__ ty, const float* __restrict__ fy,
    float* __restrict__ wsA, float* __restrict__ wsFy)
{
    __shared__ float stx[64 * 65];
    __shared__ float sfx[64 * 65];
    const int tid = threadIdx.x;
    const int ti = tid >> 4, tj = tid & 15;
    const int mat = blockIdx.x >> 2;
    const int m0 = (blockIdx.x & 3) << 6;
    const float* __restrict__ T = mat ? ty : tx;
    const float* __restrict__ F = mat ? fy : fx;
    float* __restrict__ Out = mat ? wsFy : wsA;

    float acc[4][4];
    #pragma unroll
    for (int r = 0; r < 4; ++r)
        #pragma unroll
        for (int c = 0; c < 4; ++c) acc[r][c] = 0.f;

    for (int sc = blockIdx.y; sc * 64 < 5000; sc += gridDim.y) {
        const int v0 = sc << 6;
        int vlen = 5000 - v0; if (vlen > 64) vlen = 64;
        #pragma unroll
        for (int w = 0; w < 4; ++w) {
            const int fidx = tid + (w << 8);
            const int row = fidx >> 4, q = fidx & 15;
            const int vv = q << 2;
            if (vv < vlen) {
                float4 val = *(const float4*)(T + (size_t)row * 5000 + v0 + vv);
                stx[row * 65 + vv + 0] = val.x;
                stx[row * 65 + vv + 1] = val.y;
                stx[row * 65 + vv + 2] = val.z;
                stx[row * 65 + vv + 3] = val.w;
            }
            if (row < vlen) {
                float4 val = *(const float4*)(F + (size_t)(v0 + row) * 256 + m0 + (q << 2));
                sfx[row * 65 + (q << 2) + 0] = val.x;
                sfx[row * 65 + (q << 2) + 1] = val.y;
                sfx[row * 65 + (q << 2) + 2] = val.z;
                sfx[row * 65 + (q << 2) + 3] = val.w;
            }
        }
        __syncthreads();
        for (int vv = 0; vv < vlen; ++vv) {
            float a[4], b[4];
            #pragma unroll
            for (int r = 0; r < 4; ++r) a[r] = stx[(4 * ti + r) * 65 + vv];
            #pragma unroll
            for (int c = 0; c < 4; ++c) b[c] = sfx[vv * 65 + 4 * tj + c];
            #pragma unroll
            for (int r = 0; r < 4; ++r)
                #pragma unroll
                for (int c = 0; c < 4; ++c)
                    acc[r][c] = fmaf(a[r], b[c], acc[r][c]);
        }
        __syncthreads();
    }
    #pragma unroll
    for (int r = 0; r < 4; ++r)
        #pragma unroll
        for (int c = 0; c < 4; ++c)
            atomicAdd(&Out[(4 * ti + r) * 256 + m0 + 4 * tj + c], acc[r][c]);
}

// ---- Newton-Schulz: X <- X(2I - M X). sM,sX padded LDP; sY flat 64 -------
__device__ __forceinline__ void ns_invert(float* sM, float* sX, float* sY,
                                          int iters, int ti, int tj,
                                          int tid, float alpha)
{
    for (int idx = tid; idx < 4096; idx += 256) {
        int i = idx >> 6, j = idx & 63;
        sX[i * LDP + j] = (i == j) ? alpha : 0.f;
    }
    __syncthreads();
    for (int it = 0; it < iters; ++it) {
        float y[4][4];
        #pragma unroll
        for (int r = 0; r < 4; ++r)
            #pragma unroll
            for (int c = 0; c < 4; ++c) y[r][c] = 0.f;
        mm64<LDP, LDP>(sM, sX, ti, tj, y);          // Y = M*X
        #pragma unroll
        for (int r = 0; r < 4; ++r) {
            float4 v = {y[r][0], y[r][1], y[r][2], y[r][3]};
            *(float4*)&sY[(4 * ti + r) * 64 + 4 * tj] = v;
        }
        __syncthreads();
        float z[4][4];
        #pragma unroll
        for (int r = 0; r < 4; ++r)
            #pragma unroll
            for (int c = 0; c < 4; ++c) z[r][c] = 0.f;
        mm64<LDP, 64>(sX, sY, ti, tj, z);           // Z = X*Y
        __syncthreads();
        #pragma unroll
        for (int r = 0; r < 4; ++r) {
            float4 xv = *(const float4*)&sX[(4 * ti + r) * LDP + 4 * tj];
            xv.x = 2.f * xv.x - z[r][0];
            xv.y = 2.f * xv.y - z[r][1];
            xv.z = 2.f * xv.z - z[r][2];
            xv.w = 2.f * xv.w - z[r][3];
            *(float4*)&sX[(4 * ti + r) * LDP + 4 * tj] = xv;
        }
        __syncthreads();
    }
}

// ---------------- Kernel 2: 4 specialized blocks (dynamic LDS 67840 B) ----
// lds2 layout (floats): sM 0 (pad 4352) | sX 4352 (pad 4352) | sY 8704 (4096)
//                       sA 12800 (4096) | sV 16896 (64)   -> 16960 fl
__global__ __launch_bounds__(256, 1) void k2_prep(
    const float* __restrict__ wsA, const float* __restrict__ wsFy,
    const float* __restrict__ sx, const float* __restrict__ sy,
    const float* __restrict__ ex, float* __restrict__ ws)
{
    extern __shared__ __align__(16) float lds2[];
    float* sM = lds2;
    float* sX = lds2 + 4352;
    float* sY = lds2 + 8704;
    float* sA = lds2 + 12800;
    float* sV = lds2 + 16896;
    const int tid = threadIdx.x;
    const int ti = tid >> 4, tj = tid & 15;
    const int b = blockIdx.x;

    if (b == 0 || b == 1) {
        float a[4][4];
        #pragma unroll
        for (int r = 0; r < 4; ++r)
            #pragma unroll
            for (int c = 0; c < 4; ++c) a[r][c] = 0.f;
        if (b == 0) {
            // H1 = sy^T sy (syrk from flat-staged sy, row-k-fixed f4 reads)
            for (int idx = tid; idx < 1024; idx += 256) {
                int i = idx >> 4, j4 = (idx & 15) << 2;
                *(float4*)&sA[i * 64 + j4] = *(const float4*)&sy[i * 64 + j4];
            }
            __syncthreads();
            for (int k = 0; k < 64; ++k) {
                float4 av = *(const float4*)&sA[k * 64 + 4 * ti];
                float4 bv = *(const float4*)&sA[k * 64 + 4 * tj];
                FMA4(a[0], av.x, bv); FMA4(a[1], av.y, bv);
                FMA4(a[2], av.z, bv); FMA4(a[3], av.w, bv);
            }
        } else {
            // G1 = A A^T over 4 transposed-staged chunks
            for (int ch = 0; ch < 4; ++ch) {
                for (int idx = tid; idx < 1024; idx += 256) {
                    int i = idx >> 4, m4 = (idx & 15) << 2;
                    float4 v = *(const float4*)&wsA[i * 256 + (ch << 6) + m4];
                    sA[(m4 + 0) * 64 + i] = v.x;
                    sA[(m4 + 1) * 64 + i] = v.y;
                    sA[(m4 + 2) * 64 + i] = v.z;
                    sA[(m4 + 3) * 64 + i] = v.w;
                }
                __syncthreads();
                for (int m = 0; m < 64; ++m) {
                    float4 av = *(const float4*)&sA[m * 64 + 4 * ti];
                    float4 bv = *(const float4*)&sA[m * 64 + 4 * tj];
                    FMA4(a[0], av.x, bv); FMA4(a[1], av.y, bv);
                    FMA4(a[2], av.z, bv); FMA4(a[3], av.w, bv);
                }
                __syncthreads();
            }
        }
        const int wsoff = (b == 0) ? WS_H1 : WS_G1;
        #pragma unroll
        for (int r = 0; r < 4; ++r) {
            float4 v = {a[r][0], a[r][1], a[r][2], a[r][3]};
            *(float4*)&sM[(4 * ti + r) * LDP + 4 * tj] = v;
            *(float4*)&ws[wsoff + (4 * ti + r) * 64 + 4 * tj] = v;
        }
        __syncthreads();
        // Gershgorin alpha = 1/max row-sum
        if (tid < 64) {
            float s = 0.f;
            for (int j4 = 0; j4 < 64; j4 += 4) {
                float4 v = *(const float4*)&sM[tid * LDP + j4];
                s += fabsf(v.x) + fabsf(v.y) + fabsf(v.z) + fabsf(v.w);
            }
            sV[tid] = s;
        }
        __syncthreads();
        float mx = 0.f;
        for (int i = 0; i < 64; ++i) mx = fmaxf(mx, sV[i]);
        ns_invert(sM, sX, sY, NS_SPD, ti, tj, tid, 1.0f / mx);
        const int wsinv = (b == 0) ? WS_HINV : WS_GINV;
        for (int idx = tid; idx < 1024; idx += 256) {
            int i = idx >> 4, j4 = (idx & 15) << 2;
            *(float4*)&ws[wsinv + i * 64 + j4] = *(const float4*)&sX[i * LDP + j4];
        }
    } else if (b == 2) {
        // P = inv(sx) via NS; R2 = P^T Dx P, R4 = P^T P, T1 = P^T Dx^2 P
        for (int idx = tid; idx < 1024; idx += 256) {
            int i = idx >> 4, j4 = (idx & 15) << 2;
            *(float4*)&sM[i * LDP + j4] = *(const float4*)&sx[i * 64 + j4];
        }
        if (tid < 64) sV[tid] = ex[tid];
        __syncthreads();
        ns_invert(sM, sX, sY, NS_SX, ti, tj, tid, 1.0f);
        float aR2[4][4], aR4[4][4], aT1[4][4];
        #pragma unroll
        for (int r = 0; r < 4; ++r)
            #pragma unroll
            for (int c = 0; c < 4; ++c) { aR2[r][c] = 0.f; aR4[r][c] = 0.f; aT1[r][c] = 0.f; }
        for (int k = 0; k < 64; ++k) {
            float e = sV[k], e2 = e * e;
            float4 av = *(const float4*)&sX[k * LDP + 4 * ti];
            float4 bv = *(const float4*)&sX[k * LDP + 4 * tj];
            float avv[4] = {av.x, av.y, av.z, av.w};
            #pragma unroll
            for (int r = 0; r < 4; ++r) {
                FMA4(aR4[r], avv[r], bv);
                float ea = e * avv[r];
                FMA4(aR2[r], ea, bv);
                float e2a = e2 * avv[r];
                FMA4(aT1[r], e2a, bv);
            }
        }
        #pragma unroll
        for (int r = 0; r < 4; ++r) {
            int o = (4 * ti + r) * 64 + 4 * tj;
            float4 v2 = {aR2[r][0], aR2[r][1], aR2[r][2], aR2[r][3]};
            float4 v4 = {aR4[r][0], aR4[r][1], aR4[r][2], aR4[r][3]};
            float4 v1 = {aT1[r][0], aT1[r][1], aT1[r][2], aT1[r][3]};
            *(float4*)&ws[WS_R2 + o] = v2;
            *(float4*)&ws[WS_R4 + o] = v4;
            *(float4*)&ws[WS_T1 + o] = v1;
        }
    } else {
        // FyAT = Fy A^T (4 dual-transposed chunks); H1 local; RHS = H1*FyAT
        float a[4][4];
        #pragma unroll
        for (int r = 0; r < 4; ++r)
            #pragma unroll
            for (int c = 0; c < 4; ++c) a[r][c] = 0.f;
        for (int ch = 0; ch < 4; ++ch) {
            for (int idx = tid; idx < 1024; idx += 256) {
                int i = idx >> 4, m4 = (idx & 15) << 2;
                float4 v = *(const float4*)&wsFy[i * 256 + (ch << 6) + m4];
                sA[(m4 + 0) * 64 + i] = v.x;
                sA[(m4 + 1) * 64 + i] = v.y;
                sA[(m4 + 2) * 64 + i] = v.z;
                sA[(m4 + 3) * 64 + i] = v.w;
                float4 w = *(const float4*)&wsA[i * 256 + (ch << 6) + m4];
                sY[(m4 + 0) * 64 + i] = w.x;
                sY[(m4 + 1) * 64 + i] = w.y;
                sY[(m4 + 2) * 64 + i] = w.z;
                sY[(m4 + 3) * 64 + i] = w.w;
            }
            __syncthreads();
            for (int m = 0; m < 64; ++m) {
                float4 fv = *(const float4*)&sA[m * 64 + 4 * ti];
                float4 av = *(const float4*)&sY[m * 64 + 4 * tj];
                FMA4(a[0], fv.x, av); FMA4(a[1], fv.y, av);
                FMA4(a[2], fv.z, av); FMA4(a[3], fv.w, av);
            }
            __syncthreads();
        }
        #pragma unroll
        for (int r = 0; r < 4; ++r) {
            float4 v = {a[r][0], a[r][1], a[r][2], a[r][3]};
            *(float4*)&sX[(4 * ti + r) * LDP + 4 * tj] = v;   // FyAT (B-op)
        }
        for (int idx = tid; idx < 1024; idx += 256) {
            int i = idx >> 4, j4 = (idx & 15) << 2;
            *(float4*)&sA[i * 64 + j4] = *(const float4*)&sy[i * 64 + j4];
        }
        __syncthreads();
        float h[4][4];
        #pragma unroll
        for (int r = 0; r < 4; ++r)
            #pragma unroll
            for (int c = 0; c < 4; ++c) h[r][c] = 0.f;
        for (int k = 0; k < 64; ++k) {
            float4 av = *(const float4*)&sA[k * 64 + 4 * ti];
            float4 bv = *(const float4*)&sA[k * 64 + 4 * tj];
            FMA4(h[0], av.x, bv); FMA4(h[1], av.y, bv);
            FMA4(h[2], av.z, bv); FMA4(h[3], av.w, bv);
        }
        #pragma unroll
        for (int r = 0; r < 4; ++r) {
            float4 v = {h[r][0], h[r][1], h[r][2], h[r][3]};
            *(float4*)&sM[(4 * ti + r) * LDP + 4 * tj] = v;   // H1 (A-op)
        }
        __syncthreads();
        float rh[4][4];
        #pragma unroll
        for (int r = 0; r < 4; ++r)
            #pragma unroll
            for (int c = 0; c < 4; ++c) rh[r][c] = 0.f;
        mm64<LDP, LDP>(sM, sX, ti, tj, rh);                   // RHS = H1*FyAT
        #pragma unroll
        for (int r = 0; r < 4; ++r) {
            float4 v = {rh[r][0], rh[r][1], rh[r][2], rh[r][3]};
            *(float4*)&ws[WS_RHS + (4 * ti + r) * 64 + 4 * tj] = v;
        }
    }
}

// ---------------- Kernel 3: preconditioned Richardson (dyn LDS 150528 B) ---
// lds3 layout (floats): flat B-ops: cGinv 0 | cM1 4096 | cR2 8192 | cR4 12288
//   | sT0 16384 | sT1 20480 ; padded A-ops: cHinv 24576 | sR 28928 | sX 33280
__global__ __launch_bounds__(256, 1) void k3_solve(
    const float* __restrict__ ws, const float* __restrict__ ey_g,
    float* __restrict__ out)
{
    extern __shared__ __align__(16) float lds3[];
    float* cGinv = lds3;
    float* cM1   = lds3 + 4096;
    float* cR2   = lds3 + 8192;
    float* cR4   = lds3 + 12288;
    float* sT0   = lds3 + 16384;
    float* sT1   = lds3 + 20480;
    float* cHinv = lds3 + 24576;
    float* sR    = lds3 + 28928;
    float* sX    = lds3 + 33280;
    const int tid = threadIdx.x;
    const int ti = tid >> 4, tj = tid & 15;
    const float* __restrict__ H1g = ws + WS_H1;

    // stage constants (M1 = G1 + LMBDA*T1 folded here)
    for (int idx = tid; idx < 1024; idx += 256) {
        int i = idx >> 4, j4 = (idx & 15) << 2;
        int o = i * 64 + j4;
        *(float4*)&cGinv[o] = *(const float4*)&ws[WS_GINV + o];
        *(float4*)&cR2[o]   = *(const float4*)&ws[WS_R2 + o];
        *(float4*)&cR4[o]   = *(const float4*)&ws[WS_R4 + o];
        float4 g = *(const float4*)&ws[WS_G1 + o];
        float4 t = *(const float4*)&ws[WS_T1 + o];
        float4 m = {fmaf(LMBDA, t.x, g.x), fmaf(LMBDA, t.y, g.y),
                    fmaf(LMBDA, t.z, g.z), fmaf(LMBDA, t.w, g.w)};
        *(float4*)&cM1[o] = m;
        *(float4*)&cHinv[i * LDP + j4] = *(const float4*)&ws[WS_HINV + o];
    }
    float4 eyv = *(const float4*)&ey_g[4 * ti];
    float eyr[4] = {eyv.x, eyv.y, eyv.z, eyv.w};
    float leyr[4];
    #pragma unroll
    for (int r = 0; r < 4; ++r) leyr[r] = LMBDA * eyr[r];

    float rhs[4][4];
    #pragma unroll
    for (int r = 0; r < 4; ++r) {
        float4 v = *(const float4*)&ws[WS_RHS + (4 * ti + r) * 64 + 4 * tj];
        rhs[r][0] = v.x; rhs[r][1] = v.y; rhs[r][2] = v.z; rhs[r][3] = v.w;
        *(float4*)&sR[(4 * ti + r) * LDP + 4 * tj] = v;
        float4 z = {0.f, 0.f, 0.f, 0.f};
        *(float4*)&sX[(4 * ti + r) * LDP + 4 * tj] = z;
    }
    __syncthreads();

    for (int it = 0; it < OUTER; ++it) {
        // P1: T0 = R * Ginv
        {
            float a[4][4];
            #pragma unroll
            for (int r = 0; r < 4; ++r)
                #pragma unroll
                for (int c = 0; c < 4; ++c) a[r][c] = 0.f;
            mm64<LDP, 64>(sR, cGinv, ti, tj, a);
            #pragma unroll
            for (int r = 0; r < 4; ++r) {
                float4 v = {a[r][0], a[r][1], a[r][2], a[r][3]};
                *(float4*)&sT0[(4 * ti + r) * 64 + 4 * tj] = v;
            }
        }
        __syncthreads();
        // P2: X += Hinv * T0
        {
            float a[4][4];
            #pragma unroll
            for (int r = 0; r < 4; ++r)
                #pragma unroll
                for (int c = 0; c < 4; ++c) a[r][c] = 0.f;
            mm64<LDP, 64>(cHinv, sT0, ti, tj, a);
            #pragma unroll
            for (int r = 0; r < 4; ++r) {
                float4 xv = *(const float4*)&sX[(4 * ti + r) * LDP + 4 * tj];
                xv.x += a[r][0]; xv.y += a[r][1]; xv.z += a[r][2]; xv.w += a[r][3];
                *(float4*)&sX[(4 * ti + r) * LDP + 4 * tj] = xv;
                if (it == OUTER - 1)
                    *(float4*)&out[(4 * ti + r) * 64 + 4 * tj] = xv;
            }
        }
        if (it == OUTER - 1) break;
        __syncthreads();
        // P3: Sm=X*M1, S2=X*R2, S4=X*R4 (shared A); E1,E2 combined at write
        {
            float Sm[4][4], S2[4][4], S4[4][4];
            #pragma unroll
            for (int r = 0; r < 4; ++r)
                #pragma unroll
                for (int c = 0; c < 4; ++c) { Sm[r][c] = 0.f; S2[r][c] = 0.f; S4[r][c] = 0.f; }
            #pragma unroll 2
            for (int k = 0; k < 64; k += 4) {
                float4 av[4];
                #pragma unroll
                for (int r = 0; r < 4; ++r)
                    av[r] = *(const float4*)&sX[(4 * ti + r) * LDP + k];
                #pragma unroll
                for (int q = 0; q < 4; ++q) {
                    float4 mv = *(const float4*)&cM1[(k + q) * 64 + 4 * tj];
                    float4 qv = *(const float4*)&cR2[(k + q) * 64 + 4 * tj];
                    float4 r4 = *(const float4*)&cR4[(k + q) * 64 + 4 * tj];
                    float xq[4] = {av[0].x, av[1].x, av[2].x, av[3].x};
                    if (q == 1) { xq[0] = av[0].y; xq[1] = av[1].y; xq[2] = av[2].y; xq[3] = av[3].y; }
                    if (q == 2) { xq[0] = av[0].z; xq[1] = av[1].z; xq[2] = av[2].z; xq[3] = av[3].z; }
                    if (q == 3) { xq[0] = av[0].w; xq[1] = av[1].w; xq[2] = av[2].w; xq[3] = av[3].w; }
                    #pragma unroll
                    for (int r = 0; r < 4; ++r) {
                        FMA4(Sm[r], xq[r], mv);
                        FMA4(S2[r], xq[r], qv);
                        FMA4(S4[r], xq[r], r4);
                    }
                }
            }
            #pragma unroll
            for (int r = 0; r < 4; ++r) {
                float4 t0, t1;
                t0.x = fmaf(-leyr[r], S2[r][0], Sm[r][0]);
                t0.y = fmaf(-leyr[r], S2[r][1], Sm[r][1]);
                t0.z = fmaf(-leyr[r], S2[r][2], Sm[r][2]);
                t0.w = fmaf(-leyr[r], S2[r][3], Sm[r][3]);
                t1.x = LMBDA * fmaf(eyr[r], S4[r][0], -S2[r][0]);
                t1.y = LMBDA * fmaf(eyr[r], S4[r][1], -S2[r][1]);
                t1.z = LMBDA * fmaf(eyr[r], S4[r][2], -S2[r][2]);
                t1.w = LMBDA * fmaf(eyr[r], S4[r][3], -S2[r][3]);
                *(float4*)&sT0[(4 * ti + r) * 64 + 4 * tj] = t0;
                *(float4*)&sT1[(4 * ti + r) * 64 + 4 * tj] = t1;
            }
        }
        __syncthreads();
        // P4: R = rhs - H1*T0 - D*(H1*T1)   (H1 symmetric rows from global)
        {
            float a1[4][4], a2[4][4];
            #pragma unroll
            for (int r = 0; r < 4; ++r)
                #pragma unroll
                for (int c = 0; c < 4; ++c) { a1[r][c] = 0.f; a2[r][c] = 0.f; }
            #pragma unroll 2
            for (int k = 0; k < 64; k += 4) {
                float4 hv[4];
                #pragma unroll
                for (int r = 0; r < 4; ++r)
                    hv[r] = *(const float4*)&H1g[(4 * ti + r) * 64 + k];
                #pragma unroll
                for (int q = 0; q < 4; ++q) {
                    float4 e1 = *(const float4*)&sT0[(k + q) * 64 + 4 * tj];
                    float4 e2 = *(const float4*)&sT1[(k + q) * 64 + 4 * tj];
                    float hq[4] = {hv[0].x, hv[1].x, hv[2].x, hv[3].x};
                    if (q == 1) { hq[0] = hv[0].y; hq[1] = hv[1].y; hq[2] = hv[2].y; hq[3] = hv[3].y; }
                    if (q == 2) { hq[0] = hv[0].z; hq[1] = hv[1].z; hq[2] = hv[2].z; hq[3] = hv[3].z; }
                    if (q == 3) { hq[0] = hv[0].w; hq[1] = hv[1].w; hq[2] = hv[2].w; hq[3] = hv[3].w; }
                    #pragma unroll
                    for (int r = 0; r < 4; ++r) {
                        FMA4(a1[r], hq[r], e1);
                        FMA4(a2[r], hq[r], e2);
                    }
                }
            }
            #pragma unroll
            for (int r = 0; r < 4; ++r) {
                float4 v;
                v.x = rhs[r][0] - a1[r][0] - eyr[r] * a2[r][0];
                v.y = rhs[r][1] - a1[r][1] - eyr[r] * a2[r][1];
                v.z = rhs[r][2] - a1[r][2] - eyr[r] * a2[r][2];
                v.w = rhs[r][3] - a1[r][3] - eyr[r] * a2[r][3];
                *(float4*)&sR[(4 * ti + r) * LDP + 4 * tj] = v;
            }
        }
        __syncthreads();
    }
}

extern "C" void kernel_launch(void* const* d_in, const int* in_sizes, int n_in,
                              void* d_out, int out_size, void* d_ws, size_t ws_size,
                              hipStream_t stream) {
    (void)in_sizes; (void)n_in; (void)out_size; (void)ws_size;
    const float* fx = (const float*)d_in[0];
    const float* fy = (const float*)d_in[1];
    const float* ex = (const float*)d_in[2];
    const float* ey = (const float*)d_in[3];
    const float* tx = (const float*)d_in[4];
    const float* ty = (const float*)d_in[5];
    const float* sx = (const float*)d_in[6];
    const float* sy = (const float*)d_in[7];
    float* ws = (float*)d_ws;
    float* out = (float*)d_out;

    (void)hipFuncSetAttribute((const void*)k2_prep,
                              hipFuncAttributeMaxDynamicSharedMemorySize, 67840);
    (void)hipFuncSetAttribute((const void*)k3_solve,
                              hipFuncAttributeMaxDynamicSharedMemorySize, 150528);

    (void)hipMemsetAsync(d_ws, 0, 2 * 64 * 256 * sizeof(float), stream);
    k1_gemm<<<dim3(8, 40), 256, 0, stream>>>(tx, fx, ty, fy, ws + WS_A, ws + WS_FY);
    k2_prep<<<4, 256, 67840, stream>>>(ws + WS_A, ws + WS_FY, sx, sy, ex, ws);
    k3_solve<<<1, 256, 150528, stream>>>(ws, ey, out);
}

// Round 6
// 181.481 us; speedup vs baseline: 2.1107x; 1.3175x over previous
//
#include <hip/hip_runtime.h>

#define LMBDA 0.001f
#define NS_SY 4     // NS iters for inv(sy): ||I-sy||~0.8 -> 0.8^16=0.028, lambda-damped
#define NS_G  5     // NS iters for inv(G1), Frobenius alpha (rho0~0.8 -> 8e-4)
#define NS_SX 5     // NS iters for inv(sx): enters lambda-damped R2/R4/T1
#define OUTER 3     // outer Richardson iters, rho ~ max(eps_G, 1e-3)
#define LDP 68      // padded stride for row-chunk (A-operand / dot-style) reads

// workspace layout (float offsets)
#define WS_A    0        // 64*256
#define WS_FY   16384    // 64*256
#define WS_G1   32768
#define WS_T1   36864
#define WS_R2   40960
#define WS_R4   45056
#define WS_GINV 49152
#define WS_C    53248
#define WS_FYAT 57344
// total 61440 floats = 240 KiB

#define FMA4(ar, xs, b) { ar[0]=fmaf((xs),(b).x,ar[0]); ar[1]=fmaf((xs),(b).y,ar[1]); \
                          ar[2]=fmaf((xs),(b).z,ar[2]); ar[3]=fmaf((xs),(b).w,ar[3]); }

// C-tile += A[4ti..][:] * B[:][4tj..]; all f4 (b128) LDS reads
template<int SA, int SB>
__device__ __forceinline__ void mm64(const float* __restrict__ A,
                                     const float* __restrict__ B,
                                     int ti, int tj, float a[4][4]) {
    #pragma unroll 4
    for (int k = 0; k < 64; k += 4) {
        float4 av0 = *(const float4*)&A[(4 * ti + 0) * SA + k];
        float4 av1 = *(const float4*)&A[(4 * ti + 1) * SA + k];
        float4 av2 = *(const float4*)&A[(4 * ti + 2) * SA + k];
        float4 av3 = *(const float4*)&A[(4 * ti + 3) * SA + k];
        float4 b0 = *(const float4*)&B[(k + 0) * SB + 4 * tj];
        float4 b1 = *(const float4*)&B[(k + 1) * SB + 4 * tj];
        float4 b2 = *(const float4*)&B[(k + 2) * SB + 4 * tj];
        float4 b3 = *(const float4*)&B[(k + 3) * SB + 4 * tj];
        FMA4(a[0], av0.x, b0); FMA4(a[0], av0.y, b1); FMA4(a[0], av0.z, b2); FMA4(a[0], av0.w, b3);
        FMA4(a[1], av1.x, b0); FMA4(a[1], av1.y, b1); FMA4(a[1], av1.z, b2); FMA4(a[1], av1.w, b3);
        FMA4(a[2], av2.x, b0); FMA4(a[2], av2.y, b1); FMA4(a[2], av2.z, b2); FMA4(a[2], av2.w, b3);
        FMA4(a[3], av3.x, b0); FMA4(a[3], av3.y, b1); FMA4(a[3], av3.z, b2); FMA4(a[3], av3.w, b3);
    }
}

// ---------------- Kernel 1: A = tx@fx, Fy = ty@fy  (64x5000 @ 5000x256) ----
// grid (8, 27); transposed T staging -> inner loop is 2 f4 reads / 16 FMA per v
__global__ __launch_bounds__(256) void k1_gemm(
    const float* __restrict__ tx, const float* __restrict__ fx,
    const float* __restrict__ ty, const float* __restrict__ fy,
    float* __restrict__ wsA, float* __restrict__ wsFy)
{
    __shared__ float sT[64 * LDP];   // sT[v][k]
    __shared__ float sF[64 * LDP];   // sF[v][m]
    const int tid = threadIdx.x;
    const int ti = tid >> 4, tj = tid & 15;
    const int mat = blockIdx.x >> 2;
    const int m0 = (blockIdx.x & 3) << 6;
    const float* __restrict__ T = mat ? ty : tx;
    const float* __restrict__ F = mat ? fy : fx;
    float* __restrict__ Out = mat ? wsFy : wsA;

    float acc[4][4];
    #pragma unroll
    for (int r = 0; r < 4; ++r)
        #pragma unroll
        for (int c = 0; c < 4; ++c) acc[r][c] = 0.f;

    for (int sc = blockIdx.y; sc * 64 < 5000; sc += 27) {
        const int v0 = sc << 6;
        int vlen = 5000 - v0; if (vlen > 64) vlen = 64;   // 64 or 8 (both %4==0)
        #pragma unroll
        for (int w = 0; w < 4; ++w) {
            const int fidx = tid + (w << 8);
            const int row = fidx >> 4, q = fidx & 15;
            const int vv = q << 2;
            if (vv < vlen) {   // sT[vv+i][row] = T[row, v0+vv+i]
                float4 val = *(const float4*)(T + (size_t)row * 5000 + v0 + vv);
                sT[(vv + 0) * LDP + row] = val.x;
                sT[(vv + 1) * LDP + row] = val.y;
                sT[(vv + 2) * LDP + row] = val.z;
                sT[(vv + 3) * LDP + row] = val.w;
            }
            if (row < vlen) {  // sF[row][4q..] = F[v0+row, m0+4q..]
                *(float4*)&sF[row * LDP + (q << 2)] =
                    *(const float4*)(F + (size_t)(v0 + row) * 256 + m0 + (q << 2));
            }
        }
        __syncthreads();
        for (int v = 0; v < vlen; ++v) {
            float4 av = *(const float4*)&sT[v * LDP + 4 * ti];
            float4 bv = *(const float4*)&sF[v * LDP + 4 * tj];
            FMA4(acc[0], av.x, bv); FMA4(acc[1], av.y, bv);
            FMA4(acc[2], av.z, bv); FMA4(acc[3], av.w, bv);
        }
        __syncthreads();
    }
    #pragma unroll
    for (int r = 0; r < 4; ++r)
        #pragma unroll
        for (int c = 0; c < 4; ++c)
            atomicAdd(&Out[(4 * ti + r) * 256 + m0 + 4 * tj + c], acc[r][c]);
}

// ---- Newton-Schulz: X <- X(2I - M X), X0 = alpha*I. sM,sX pad; sY flat ----
__device__ __forceinline__ void ns_invert(float* sM, float* sX, float* sY,
                                          int iters, int ti, int tj,
                                          int tid, float alpha)
{
    for (int idx = tid; idx < 4096; idx += 256) {
        int i = idx >> 6, j = idx & 63;
        sX[i * LDP + j] = (i == j) ? alpha : 0.f;
    }
    __syncthreads();
    for (int it = 0; it < iters; ++it) {
        float y[4][4];
        #pragma unroll
        for (int r = 0; r < 4; ++r)
            #pragma unroll
            for (int c = 0; c < 4; ++c) y[r][c] = 0.f;
        mm64<LDP, LDP>(sM, sX, ti, tj, y);          // Y = M*X
        #pragma unroll
        for (int r = 0; r < 4; ++r) {
            float4 v = {y[r][0], y[r][1], y[r][2], y[r][3]};
            *(float4*)&sY[(4 * ti + r) * 64 + 4 * tj] = v;
        }
        __syncthreads();
        float z[4][4];
        #pragma unroll
        for (int r = 0; r < 4; ++r)
            #pragma unroll
            for (int c = 0; c < 4; ++c) z[r][c] = 0.f;
        mm64<LDP, 64>(sX, sY, ti, tj, z);           // Z = X*Y
        __syncthreads();
        #pragma unroll
        for (int r = 0; r < 4; ++r) {
            float4 xv = *(const float4*)&sX[(4 * ti + r) * LDP + 4 * tj];
            xv.x = 2.f * xv.x - z[r][0];
            xv.y = 2.f * xv.y - z[r][1];
            xv.z = 2.f * xv.z - z[r][2];
            xv.w = 2.f * xv.w - z[r][3];
            *(float4*)&sX[(4 * ti + r) * LDP + 4 * tj] = xv;
        }
        __syncthreads();
    }
}

// ---------------- Kernel 2: 4 specialized blocks (dyn LDS 69120 B) --------
// b0: Sinv=NS(sy); Hinv=Sinv Sinv^T; H1=sy^T sy; C=Hinv*D*H1 -> ws
// b1: G1=A A^T -> ws; Ginv=NS(G1, Frobenius alpha) -> ws
// b2: P=NS(sx); R2/R4/T1 -> ws          b3: FyAT=Fy A^T -> ws
__global__ __launch_bounds__(256, 1) void k2_prep(
    const float* __restrict__ wsA, const float* __restrict__ wsFy,
    const float* __restrict__ sx, const float* __restrict__ sy,
    const float* __restrict__ ex, const float* __restrict__ ey,
    float* __restrict__ ws)
{
    extern __shared__ __align__(16) float lds2[];
    const int tid = threadIdx.x;
    const int ti = tid >> 4, tj = tid & 15;
    const int b = blockIdx.x;

    if (b == 0) {
        float* sSy = lds2;            // pad: sy, later Hinv
        float* sXx = lds2 + 4352;     // pad: NS X -> Sinv
        float* sYy = lds2 + 8704;     // flat: NS tmp
        float* sH  = lds2 + 12800;    // flat: H1
        float* sV  = lds2 + 16896;    // ey
        for (int idx = tid; idx < 1024; idx += 256) {
            int i = idx >> 4, j4 = (idx & 15) << 2;
            *(float4*)&sSy[i * LDP + j4] = *(const float4*)&sy[i * 64 + j4];
        }
        if (tid < 64) sV[tid] = ey[tid];
        __syncthreads();
        // H1 = sy^T sy (outer-product syrk, k-fixed f4 reads)
        {
            float h[4][4];
            #pragma unroll
            for (int r = 0; r < 4; ++r)
                #pragma unroll
                for (int c = 0; c < 4; ++c) h[r][c] = 0.f;
            for (int k = 0; k < 64; ++k) {
                float4 av = *(const float4*)&sSy[k * LDP + 4 * ti];
                float4 bv = *(const float4*)&sSy[k * LDP + 4 * tj];
                FMA4(h[0], av.x, bv); FMA4(h[1], av.y, bv);
                FMA4(h[2], av.z, bv); FMA4(h[3], av.w, bv);
            }
            #pragma unroll
            for (int r = 0; r < 4; ++r) {
                float4 v = {h[r][0], h[r][1], h[r][2], h[r][3]};
                *(float4*)&sH[(4 * ti + r) * 64 + 4 * tj] = v;
            }
        }
        __syncthreads();
        ns_invert(sSy, sXx, sYy, NS_SY, ti, tj, tid, 1.0f);   // Sinv
        // Hinv = Sinv Sinv^T (dot-style) -> overwrite sSy (sy dead)
        {
            float h[4][4];
            #pragma unroll
            for (int r = 0; r < 4; ++r)
                #pragma unroll
                for (int c = 0; c < 4; ++c) h[r][c] = 0.f;
            for (int m = 0; m < 64; m += 4) {
                float4 av[4], bv[4];
                #pragma unroll
                for (int r = 0; r < 4; ++r) av[r] = *(const float4*)&sXx[(4 * ti + r) * LDP + m];
                #pragma unroll
                for (int c = 0; c < 4; ++c) bv[c] = *(const float4*)&sXx[(4 * tj + c) * LDP + m];
                #pragma unroll
                for (int r = 0; r < 4; ++r)
                    #pragma unroll
                    for (int c = 0; c < 4; ++c)
                        h[r][c] += av[r].x * bv[c].x + av[r].y * bv[c].y
                                 + av[r].z * bv[c].z + av[r].w * bv[c].w;
            }
            __syncthreads();
            #pragma unroll
            for (int r = 0; r < 4; ++r) {
                float4 v = {h[r][0], h[r][1], h[r][2], h[r][3]};
                *(float4*)&sSy[(4 * ti + r) * LDP + 4 * tj] = v;
            }
        }
        __syncthreads();
        // C = Hinv * (D H1): B-rows of H1 scaled by ey[k]
        {
            float a[4][4];
            #pragma unroll
            for (int r = 0; r < 4; ++r)
                #pragma unroll
                for (int c = 0; c < 4; ++c) a[r][c] = 0.f;
            #pragma unroll 4
            for (int k = 0; k < 64; k += 4) {
                float4 av[4];
                #pragma unroll
                for (int r = 0; r < 4; ++r) av[r] = *(const float4*)&sSy[(4 * ti + r) * LDP + k];
                #pragma unroll
                for (int q = 0; q < 4; ++q) {
                    float e = sV[k + q];
                    float4 bv = *(const float4*)&sH[(k + q) * 64 + 4 * tj];
                    bv.x *= e; bv.y *= e; bv.z *= e; bv.w *= e;
                    float xq[4] = {av[0].x, av[1].x, av[2].x, av[3].x};
                    if (q == 1) { xq[0]=av[0].y; xq[1]=av[1].y; xq[2]=av[2].y; xq[3]=av[3].y; }
                    if (q == 2) { xq[0]=av[0].z; xq[1]=av[1].z; xq[2]=av[2].z; xq[3]=av[3].z; }
                    if (q == 3) { xq[0]=av[0].w; xq[1]=av[1].w; xq[2]=av[2].w; xq[3]=av[3].w; }
                    #pragma unroll
                    for (int r = 0; r < 4; ++r) FMA4(a[r], xq[r], bv);
                }
            }
            #pragma unroll
            for (int r = 0; r < 4; ++r) {
                float4 v = {a[r][0], a[r][1], a[r][2], a[r][3]};
                *(float4*)&ws[WS_C + (4 * ti + r) * 64 + 4 * tj] = v;
            }
        }
    } else if (b == 1) {
        float* sA = lds2;             // pad: staging chunk
        float* sG = lds2 + 4352;      // pad: G1
        float* sX = lds2 + 8704;      // pad: NS X
        float* sY = lds2 + 13056;     // flat: NS tmp
        float* sV = lds2 + 17152;     // 128: Frobenius reduce
        float a[4][4];
        #pragma unroll
        for (int r = 0; r < 4; ++r)
            #pragma unroll
            for (int c = 0; c < 4; ++c) a[r][c] = 0.f;
        for (int ch = 0; ch < 4; ++ch) {
            for (int idx = tid; idx < 1024; idx += 256) {
                int i = idx >> 4, m4 = (idx & 15) << 2;
                *(float4*)&sA[i * LDP + m4] =
                    *(const float4*)&wsA[i * 256 + (ch << 6) + m4];
            }
            __syncthreads();
            for (int m = 0; m < 64; m += 4) {
                float4 av[4], bv[4];
                #pragma unroll
                for (int r = 0; r < 4; ++r) av[r] = *(const float4*)&sA[(4 * ti + r) * LDP + m];
                #pragma unroll
                for (int c = 0; c < 4; ++c) bv[c] = *(const float4*)&sA[(4 * tj + c) * LDP + m];
                #pragma unroll
                for (int r = 0; r < 4; ++r)
                    #pragma unroll
                    for (int c = 0; c < 4; ++c)
                        a[r][c] += av[r].x * bv[c].x + av[r].y * bv[c].y
                                 + av[r].z * bv[c].z + av[r].w * bv[c].w;
            }
            __syncthreads();
        }
        #pragma unroll
        for (int r = 0; r < 4; ++r) {
            float4 v = {a[r][0], a[r][1], a[r][2], a[r][3]};
            *(float4*)&sG[(4 * ti + r) * LDP + 4 * tj] = v;
            *(float4*)&ws[WS_G1 + (4 * ti + r) * 64 + 4 * tj] = v;
        }
        __syncthreads();
        // Frobenius-optimal alpha = tr(G1)/||G1||_F^2
        if (tid < 64) {
            float s = 0.f;
            for (int j4 = 0; j4 < 64; j4 += 4) {
                float4 v = *(const float4*)&sG[tid * LDP + j4];
                s += v.x * v.x + v.y * v.y + v.z * v.z + v.w * v.w;
            }
            sV[tid] = s;
            sV[64 + tid] = sG[tid * LDP + tid];
        }
        __syncthreads();
        float f2 = 0.f, tr = 0.f;
        for (int i = 0; i < 64; ++i) { f2 += sV[i]; tr += sV[64 + i]; }
        ns_invert(sG, sX, sY, NS_G, ti, tj, tid, tr / f2);
        for (int idx = tid; idx < 1024; idx += 256) {
            int i = idx >> 4, j4 = (idx & 15) << 2;
            *(float4*)&ws[WS_GINV + i * 64 + j4] = *(const float4*)&sX[i * LDP + j4];
        }
    } else if (b == 2) {
        float* sM = lds2;             // pad: sx
        float* sX = lds2 + 4352;      // pad: P
        float* sY = lds2 + 8704;      // flat
        float* sV = lds2 + 12800;     // ex
        for (int idx = tid; idx < 1024; idx += 256) {
            int i = idx >> 4, j4 = (idx & 15) << 2;
            *(float4*)&sM[i * LDP + j4] = *(const float4*)&sx[i * 64 + j4];
        }
        if (tid < 64) sV[tid] = ex[tid];
        __syncthreads();
        ns_invert(sM, sX, sY, NS_SX, ti, tj, tid, 1.0f);
        float aR2[4][4], aR4[4][4], aT1[4][4];
        #pragma unroll
        for (int r = 0; r < 4; ++r)
            #pragma unroll
            for (int c = 0; c < 4; ++c) { aR2[r][c] = 0.f; aR4[r][c] = 0.f; aT1[r][c] = 0.f; }
        for (int k = 0; k < 64; ++k) {
            float e = sV[k], e2 = e * e;
            float4 av = *(const float4*)&sX[k * LDP + 4 * ti];
            float4 bv = *(const float4*)&sX[k * LDP + 4 * tj];
            float avv[4] = {av.x, av.y, av.z, av.w};
            #pragma unroll
            for (int r = 0; r < 4; ++r) {
                FMA4(aR4[r], avv[r], bv);
                float ea = e * avv[r];
                FMA4(aR2[r], ea, bv);
                float e2a = e2 * avv[r];
                FMA4(aT1[r], e2a, bv);
            }
        }
        #pragma unroll
        for (int r = 0; r < 4; ++r) {
            int o = (4 * ti + r) * 64 + 4 * tj;
            float4 v2 = {aR2[r][0], aR2[r][1], aR2[r][2], aR2[r][3]};
            float4 v4 = {aR4[r][0], aR4[r][1], aR4[r][2], aR4[r][3]};
            float4 v1 = {aT1[r][0], aT1[r][1], aT1[r][2], aT1[r][3]};
            *(float4*)&ws[WS_R2 + o] = v2;
            *(float4*)&ws[WS_R4 + o] = v4;
            *(float4*)&ws[WS_T1 + o] = v1;
        }
    } else {
        // b3: FyAT = Fy A^T (dot-style over 4 chunks)
        float* sFy = lds2;            // pad
        float* sAx = lds2 + 4352;     // pad
        float a[4][4];
        #pragma unroll
        for (int r = 0; r < 4; ++r)
            #pragma unroll
            for (int c = 0; c < 4; ++c) a[r][c] = 0.f;
        for (int ch = 0; ch < 4; ++ch) {
            for (int idx = tid; idx < 1024; idx += 256) {
                int i = idx >> 4, m4 = (idx & 15) << 2;
                *(float4*)&sFy[i * LDP + m4] = *(const float4*)&wsFy[i * 256 + (ch << 6) + m4];
                *(float4*)&sAx[i * LDP + m4] = *(const float4*)&wsA[i * 256 + (ch << 6) + m4];
            }
            __syncthreads();
            for (int m = 0; m < 64; m += 4) {
                float4 av[4], bv[4];
                #pragma unroll
                for (int r = 0; r < 4; ++r) av[r] = *(const float4*)&sFy[(4 * ti + r) * LDP + m];
                #pragma unroll
                for (int c = 0; c < 4; ++c) bv[c] = *(const float4*)&sAx[(4 * tj + c) * LDP + m];
                #pragma unroll
                for (int r = 0; r < 4; ++r)
                    #pragma unroll
                    for (int c = 0; c < 4; ++c)
                        a[r][c] += av[r].x * bv[c].x + av[r].y * bv[c].y
                                 + av[r].z * bv[c].z + av[r].w * bv[c].w;
            }
            __syncthreads();
        }
        #pragma unroll
        for (int r = 0; r < 4; ++r) {
            float4 v = {a[r][0], a[r][1], a[r][2], a[r][3]};
            *(float4*)&ws[WS_FYAT + (4 * ti + r) * 64 + 4 * tj] = v;
        }
    }
}

// ---------------- Kernel 3: hybrid residual Richardson (dyn 134144 B) -----
// X += (FyAT - E1 - C*E2)*Ginv ; E1 = X M1 - l D(X R2); E2 = l(D(X R4) - X R2)
__global__ __launch_bounds__(256, 1) void k3_solve(
    const float* __restrict__ ws, const float* __restrict__ ey_g,
    float* __restrict__ out)
{
    extern __shared__ __align__(16) float lds3[];
    float* cM1   = lds3;              // flat
    float* cR2   = lds3 + 4096;      // flat
    float* cR4   = lds3 + 8192;      // flat
    float* cGinv = lds3 + 12288;     // flat
    float* sE    = lds3 + 16384;     // flat (E2)
    float* sX    = lds3 + 20480;     // pad
    float* cC    = lds3 + 24832;     // pad
    float* sW    = lds3 + 29184;     // pad
    const int tid = threadIdx.x;
    const int ti = tid >> 4, tj = tid & 15;

    for (int idx = tid; idx < 1024; idx += 256) {
        int i = idx >> 4, j4 = (idx & 15) << 2;
        int o = i * 64 + j4;
        float4 g = *(const float4*)&ws[WS_G1 + o];
        float4 t = *(const float4*)&ws[WS_T1 + o];
        float4 m = {fmaf(LMBDA, t.x, g.x), fmaf(LMBDA, t.y, g.y),
                    fmaf(LMBDA, t.z, g.z), fmaf(LMBDA, t.w, g.w)};
        *(float4*)&cM1[o]   = m;
        *(float4*)&cR2[o]   = *(const float4*)&ws[WS_R2 + o];
        *(float4*)&cR4[o]   = *(const float4*)&ws[WS_R4 + o];
        *(float4*)&cGinv[o] = *(const float4*)&ws[WS_GINV + o];
        *(float4*)&cC[i * LDP + j4] = *(const float4*)&ws[WS_C + o];
    }
    float4 eyv = *(const float4*)&ey_g[4 * ti];
    float eyr[4] = {eyv.x, eyv.y, eyv.z, eyv.w};
    float leyr[4];
    #pragma unroll
    for (int r = 0; r < 4; ++r) leyr[r] = LMBDA * eyr[r];

    float fyr[4][4], xreg[4][4];
    #pragma unroll
    for (int r = 0; r < 4; ++r) {
        float4 v = *(const float4*)&ws[WS_FYAT + (4 * ti + r) * 64 + 4 * tj];
        fyr[r][0] = v.x; fyr[r][1] = v.y; fyr[r][2] = v.z; fyr[r][3] = v.w;
        float4 z = {0.f, 0.f, 0.f, 0.f};
        *(float4*)&sX[(4 * ti + r) * LDP + 4 * tj] = z;
        #pragma unroll
        for (int c = 0; c < 4; ++c) xreg[r][c] = 0.f;
    }
    __syncthreads();

    float E1[4][4];
    for (int it = 0; it < OUTER; ++it) {
        // grp1: Sm=X*M1, S2=X*R2, S4=X*R4 (shared A-reads)
        {
            float Sm[4][4], S2[4][4], S4[4][4];
            #pragma unroll
            for (int r = 0; r < 4; ++r)
                #pragma unroll
                for (int c = 0; c < 4; ++c) { Sm[r][c] = 0.f; S2[r][c] = 0.f; S4[r][c] = 0.f; }
            #pragma unroll 2
            for (int k = 0; k < 64; k += 4) {
                float4 av[4];
                #pragma unroll
                for (int r = 0; r < 4; ++r)
                    av[r] = *(const float4*)&sX[(4 * ti + r) * LDP + k];
                #pragma unroll
                for (int q = 0; q < 4; ++q) {
                    float4 mv = *(const float4*)&cM1[(k + q) * 64 + 4 * tj];
                    float4 qv = *(const float4*)&cR2[(k + q) * 64 + 4 * tj];
                    float4 rv = *(const float4*)&cR4[(k + q) * 64 + 4 * tj];
                    float xq[4] = {av[0].x, av[1].x, av[2].x, av[3].x};
                    if (q == 1) { xq[0]=av[0].y; xq[1]=av[1].y; xq[2]=av[2].y; xq[3]=av[3].y; }
                    if (q == 2) { xq[0]=av[0].z; xq[1]=av[1].z; xq[2]=av[2].z; xq[3]=av[3].z; }
                    if (q == 3) { xq[0]=av[0].w; xq[1]=av[1].w; xq[2]=av[2].w; xq[3]=av[3].w; }
                    #pragma unroll
                    for (int r = 0; r < 4; ++r) {
                        FMA4(Sm[r], xq[r], mv);
                        FMA4(S2[r], xq[r], qv);
                        FMA4(S4[r], xq[r], rv);
                    }
                }
            }
            #pragma unroll
            for (int r = 0; r < 4; ++r) {
                float4 e2;
                e2.x = LMBDA * fmaf(eyr[r], S4[r][0], -S2[r][0]);
                e2.y = LMBDA * fmaf(eyr[r], S4[r][1], -S2[r][1]);
                e2.z = LMBDA * fmaf(eyr[r], S4[r][2], -S2[r][2]);
                e2.w = LMBDA * fmaf(eyr[r], S4[r][3], -S2[r][3]);
                *(float4*)&sE[(4 * ti + r) * 64 + 4 * tj] = e2;
                #pragma unroll
                for (int c = 0; c < 4; ++c)
                    E1[r][c] = fmaf(-leyr[r], S2[r][c], Sm[r][c]);
            }
        }
        __syncthreads();
        // grp2: Z = C*E2 ; W = FyAT - E1 - Z
        {
            float Z[4][4];
            #pragma unroll
            for (int r = 0; r < 4; ++r)
                #pragma unroll
                for (int c = 0; c < 4; ++c) Z[r][c] = 0.f;
            mm64<LDP, 64>(cC, sE, ti, tj, Z);
            #pragma unroll
            for (int r = 0; r < 4; ++r) {
                float4 w;
                w.x = fyr[r][0] - E1[r][0] - Z[r][0];
                w.y = fyr[r][1] - E1[r][1] - Z[r][1];
                w.z = fyr[r][2] - E1[r][2] - Z[r][2];
                w.w = fyr[r][3] - E1[r][3] - Z[r][3];
                *(float4*)&sW[(4 * ti + r) * LDP + 4 * tj] = w;
            }
        }
        __syncthreads();
        // grp3: dX = W*Ginv ; X += dX
        {
            float dX[4][4];
            #pragma unroll
            for (int r = 0; r < 4; ++r)
                #pragma unroll
                for (int c = 0; c < 4; ++c) dX[r][c] = 0.f;
            mm64<LDP, 64>(sW, cGinv, ti, tj, dX);
            #pragma unroll
            for (int r = 0; r < 4; ++r) {
                float4 v;
                #pragma unroll
                for (int c = 0; c < 4; ++c) xreg[r][c] += dX[r][c];
                v.x = xreg[r][0]; v.y = xreg[r][1]; v.z = xreg[r][2]; v.w = xreg[r][3];
                *(float4*)&sX[(4 * ti + r) * LDP + 4 * tj] = v;
                if (it == OUTER - 1)
                    *(float4*)&out[(4 * ti + r) * 64 + 4 * tj] = v;
            }
        }
        if (it == OUTER - 1) break;
        __syncthreads();
    }
}

extern "C" void kernel_launch(void* const* d_in, const int* in_sizes, int n_in,
                              void* d_out, int out_size, void* d_ws, size_t ws_size,
                              hipStream_t stream) {
    (void)in_sizes; (void)n_in; (void)out_size; (void)ws_size;
    const float* fx = (const float*)d_in[0];
    const float* fy = (const float*)d_in[1];
    const float* ex = (const float*)d_in[2];
    const float* ey = (const float*)d_in[3];
    const float* tx = (const float*)d_in[4];
    const float* ty = (const float*)d_in[5];
    const float* sx = (const float*)d_in[6];
    const float* sy = (const float*)d_in[7];
    float* ws = (float*)d_ws;
    float* out = (float*)d_out;

    (void)hipFuncSetAttribute((const void*)k2_prep,
                              hipFuncAttributeMaxDynamicSharedMemorySize, 69120);
    (void)hipFuncSetAttribute((const void*)k3_solve,
                              hipFuncAttributeMaxDynamicSharedMemorySize, 134144);

    (void)hipMemsetAsync(d_ws, 0, 2 * 64 * 256 * sizeof(float), stream);
    k1_gemm<<<dim3(8, 27), 256, 0, stream>>>(tx, fx, ty, fy, ws + WS_A, ws + WS_FY);
    k2_prep<<<4, 256, 69120, stream>>>(ws + WS_A, ws + WS_FY, sx, sy, ex, ey, ws);
    k3_solve<<<1, 256, 134144, stream>>>(ws, ey, out);
}